// Round 1
// baseline (493.779 us; speedup 1.0000x reference)
//
#include <hip/hip_runtime.h>
#include <math.h>

#define F1 16
#define F2 8

__global__ void k_init_deg(float* __restrict__ deg, int N) {
    int i = blockIdx.x * blockDim.x + threadIdx.x;
    if (i < N) deg[i] = 1.0f;
}

__global__ void k_deg_accum(const int* __restrict__ dst, float* __restrict__ deg, int E) {
    int e = blockIdx.x * blockDim.x + threadIdx.x;
    if (e < E) atomicAdd(&deg[dst[e]], 1.0f);
}

// dinv = rsqrt(deg); x1 init = dinv^2 * W1 (self-loop term of conv1)
__global__ void k_dinv_initx1(const float* __restrict__ deg, float* __restrict__ dinv,
                              const float* __restrict__ W1, float* __restrict__ x1, int N) {
    int i = blockIdx.x * blockDim.x + threadIdx.x;
    if (i < N) {
        float di = rsqrtf(deg[i]);
        dinv[i] = di;
        float sw = di * di;
        #pragma unroll
        for (int f = 0; f < F1; ++f)
            x1[i * F1 + f] = sw * W1[i * F1 + f];
    }
}

// edge-parallel aggregation for conv1: x1[dst] += norm * W1[src]
__global__ void k_conv1_edges(const int* __restrict__ src, const int* __restrict__ dst,
                              const float* __restrict__ dinv, const float* __restrict__ W1,
                              float* __restrict__ x1, int E) {
    int id = blockIdx.x * blockDim.x + threadIdx.x;
    int e = id >> 4;
    int f = id & (F1 - 1);
    if (e < E) {
        int s = src[e], d = dst[e];
        float nrm = dinv[s] * dinv[d];
        atomicAdd(&x1[d * F1 + f], nrm * W1[s * F1 + f]);
    }
}

// x1 := relu(x1 + b1); h2 := x1 @ W2; x2 init := dinv^2 * h2
__global__ void k_layer1_finish(const float* __restrict__ dinv, const float* __restrict__ b1,
                                const float* __restrict__ W2, const float* __restrict__ x1,
                                float* __restrict__ h2, float* __restrict__ x2, int N) {
    int i = blockIdx.x * blockDim.x + threadIdx.x;
    if (i < N) {
        float r[F1];
        #pragma unroll
        for (int f = 0; f < F1; ++f) {
            float v = x1[i * F1 + f] + b1[f];
            r[f] = v > 0.0f ? v : 0.0f;
        }
        float di = dinv[i];
        float sw = di * di;
        #pragma unroll
        for (int g = 0; g < F2; ++g) {
            float acc = 0.0f;
            #pragma unroll
            for (int f = 0; f < F1; ++f)
                acc += r[f] * W2[f * F2 + g];
            h2[i * F2 + g] = acc;
            x2[i * F2 + g] = sw * acc;
        }
    }
}

// edge-parallel aggregation for conv2: x2[dst] += norm * h2[src]
__global__ void k_conv2_edges(const int* __restrict__ src, const int* __restrict__ dst,
                              const float* __restrict__ dinv, const float* __restrict__ h2,
                              float* __restrict__ x2, int E) {
    int id = blockIdx.x * blockDim.x + threadIdx.x;
    int e = id >> 3;
    int g = id & (F2 - 1);
    if (e < E) {
        int s = src[e], d = dst[e];
        float nrm = dinv[s] * dinv[d];
        atomicAdd(&x2[d * F2 + g], nrm * h2[s * F2 + g]);
    }
}

// x2 := relu(x2 + b2)
__global__ void k_layer2_finish(const float* __restrict__ b2, float* __restrict__ x2, int N) {
    int id = blockIdx.x * blockDim.x + threadIdx.x;
    if (id < N * F2) {
        int g = id & (F2 - 1);
        float v = x2[id] + b2[g];
        x2[id] = v > 0.0f ? v : 0.0f;
    }
}

// vectorized copy adjacency -> out (the HBM-bound bulk of the work)
__global__ void k_copy(const float4* __restrict__ a, float4* __restrict__ o, long n4) {
    long i = (long)blockIdx.x * blockDim.x + threadIdx.x;
    if (i < n4) o[i] = a[i];
}

// score each undirected edge, scatter orient / 1-orient
__global__ void k_orient(const int* __restrict__ ue, const float* __restrict__ x2,
                         const float* __restrict__ Wfc, const float* __restrict__ bfc,
                         float* __restrict__ out, int U, int N) {
    int k = blockIdx.x * blockDim.x + threadIdx.x;
    if (k < U) {
        int u = ue[2 * k];
        int v = ue[2 * k + 1];
        float s = bfc[0];
        #pragma unroll
        for (int g = 0; g < F2; ++g) {
            s += x2[u * F2 + g] * Wfc[g];
            s += x2[v * F2 + g] * Wfc[F2 + g];
        }
        float orient = 1.0f / (1.0f + expf(-s));
        out[(long)u * N + v] = orient;
        out[(long)v * N + u] = 1.0f - orient;
    }
}

extern "C" void kernel_launch(void* const* d_in, const int* in_sizes, int n_in,
                              void* d_out, int out_size, void* d_ws, size_t ws_size,
                              hipStream_t stream) {
    const float* adj = (const float*)d_in[0];
    const float* W1  = (const float*)d_in[1];
    const float* b1  = (const float*)d_in[2];
    const float* W2  = (const float*)d_in[3];
    const float* b2  = (const float*)d_in[4];
    const float* Wfc = (const float*)d_in[5];
    const float* bfc = (const float*)d_in[6];
    const int* edge_index = (const int*)d_in[7];
    const int* und        = (const int*)d_in[8];

    int N = in_sizes[1] / F1;      // 8192
    int E = in_sizes[7] / 2;
    int U = in_sizes[8] / 2;
    const int* src = edge_index;
    const int* dst = edge_index + E;

    float* ws   = (float*)d_ws;
    float* deg  = ws;              // N
    float* dinv = ws + N;          // N
    float* x1   = ws + 2 * N;      // 16N
    float* h2   = x1 + (long)F1 * N;   // 8N
    float* x2   = h2 + (long)F2 * N;   // 8N

    const int B = 256;

    // degree + dinv
    k_init_deg<<<(N + B - 1) / B, B, 0, stream>>>(deg, N);
    k_deg_accum<<<(E + B - 1) / B, B, 0, stream>>>(dst, deg, E);
    k_dinv_initx1<<<(N + B - 1) / B, B, 0, stream>>>(deg, dinv, W1, x1, N);

    // conv1 + layer1
    {
        long work = (long)E * F1;
        k_conv1_edges<<<(work + B - 1) / B, B, 0, stream>>>(src, dst, dinv, W1, x1, E);
    }
    k_layer1_finish<<<(N + B - 1) / B, B, 0, stream>>>(dinv, b1, W2, x1, h2, x2, N);

    // conv2 + layer2
    {
        long work = (long)E * F2;
        k_conv2_edges<<<(work + B - 1) / B, B, 0, stream>>>(src, dst, dinv, h2, x2, E);
    }
    k_layer2_finish<<<(N * F2 + B - 1) / B, B, 0, stream>>>(b2, x2, N);

    // bulk copy adjacency -> out
    {
        long n4 = (long)N * N / 4;
        long blocks = (n4 + B - 1) / B;
        k_copy<<<(int)blocks, B, 0, stream>>>((const float4*)adj, (float4*)d_out, n4);
    }

    // edge orientation scatter
    k_orient<<<(U + B - 1) / B, B, 0, stream>>>(und, x2, Wfc, bfc, (float*)d_out, U, N);
}

// Round 2
// 455.527 us; speedup vs baseline: 1.0840x; 1.0840x over previous
//
#include <hip/hip_runtime.h>
#include <math.h>

#define F1 16
#define F2 8

__global__ void k_init_deg(float* __restrict__ deg, int N) {
    int i = blockIdx.x * blockDim.x + threadIdx.x;
    if (i < N) deg[i] = 1.0f;
}

__global__ void k_deg_accum(const int* __restrict__ dst, float* __restrict__ deg, int E) {
    int e = blockIdx.x * blockDim.x + threadIdx.x;
    if (e < E) atomicAdd(&deg[dst[e]], 1.0f);
}

// dinv = rsqrt(deg); x1 init = dinv^2 * W1 (self-loop term of conv1)
__global__ void k_dinv_initx1(const float* __restrict__ deg, float* __restrict__ dinv,
                              const float* __restrict__ W1, float* __restrict__ x1, int N) {
    int i = blockIdx.x * blockDim.x + threadIdx.x;
    if (i < N) {
        float di = rsqrtf(deg[i]);
        dinv[i] = di;
        float sw = di * di;
        #pragma unroll
        for (int f = 0; f < F1; ++f)
            x1[i * F1 + f] = sw * W1[i * F1 + f];
    }
}

// edge-parallel aggregation for conv1: x1[dst] += norm * W1[src]
__global__ void k_conv1_edges(const int* __restrict__ src, const int* __restrict__ dst,
                              const float* __restrict__ dinv, const float* __restrict__ W1,
                              float* __restrict__ x1, int E) {
    int id = blockIdx.x * blockDim.x + threadIdx.x;
    int e = id >> 4;
    int f = id & (F1 - 1);
    if (e < E) {
        int s = src[e], d = dst[e];
        float nrm = dinv[s] * dinv[d];
        atomicAdd(&x1[d * F1 + f], nrm * W1[s * F1 + f]);
    }
}

// x1 := relu(x1 + b1); h2 := x1 @ W2; x2 init := dinv^2 * h2
__global__ void k_layer1_finish(const float* __restrict__ dinv, const float* __restrict__ b1,
                                const float* __restrict__ W2, const float* __restrict__ x1,
                                float* __restrict__ h2, float* __restrict__ x2, int N) {
    int i = blockIdx.x * blockDim.x + threadIdx.x;
    if (i < N) {
        float r[F1];
        #pragma unroll
        for (int f = 0; f < F1; ++f) {
            float v = x1[i * F1 + f] + b1[f];
            r[f] = v > 0.0f ? v : 0.0f;
        }
        float di = dinv[i];
        float sw = di * di;
        #pragma unroll
        for (int g = 0; g < F2; ++g) {
            float acc = 0.0f;
            #pragma unroll
            for (int f = 0; f < F1; ++f)
                acc += r[f] * W2[f * F2 + g];
            h2[i * F2 + g] = acc;
            x2[i * F2 + g] = sw * acc;
        }
    }
}

// edge-parallel aggregation for conv2: x2[dst] += norm * h2[src]
__global__ void k_conv2_edges(const int* __restrict__ src, const int* __restrict__ dst,
                              const float* __restrict__ dinv, const float* __restrict__ h2,
                              float* __restrict__ x2, int E) {
    int id = blockIdx.x * blockDim.x + threadIdx.x;
    int e = id >> 3;
    int g = id & (F2 - 1);
    if (e < E) {
        int s = src[e], d = dst[e];
        float nrm = dinv[s] * dinv[d];
        atomicAdd(&x2[d * F2 + g], nrm * h2[s * F2 + g]);
    }
}

// write-only zero fill of the 8192x8192 output (no adjacency read needed:
// edge_index reconstructs A exactly since A is 0/1)
__global__ void k_fill_zero(float4* __restrict__ o, long n4) {
    long i = (long)blockIdx.x * blockDim.x + threadIdx.x;
    if (i < n4) o[i] = make_float4(0.f, 0.f, 0.f, 0.f);
}

// scatter 1.0 at every directed-edge position
__global__ void k_scatter_ones(const int* __restrict__ src, const int* __restrict__ dst,
                               float* __restrict__ out, int E, int N) {
    int e = blockIdx.x * blockDim.x + threadIdx.x;
    if (e < E) {
        out[(long)src[e] * N + dst[e]] = 1.0f;
    }
}

// score each undirected edge (bias+relu applied inline), scatter orient / 1-orient
__global__ void k_orient(const int2* __restrict__ ue, const float* __restrict__ x2,
                         const float* __restrict__ b2, const float* __restrict__ Wfc,
                         const float* __restrict__ bfc, float* __restrict__ out,
                         int U, int N) {
    int k = blockIdx.x * blockDim.x + threadIdx.x;
    if (k < U) {
        int2 e = ue[k];
        int u = e.x, v = e.y;
        float s = bfc[0];
        #pragma unroll
        for (int g = 0; g < F2; ++g) {
            float xu = x2[u * F2 + g] + b2[g];
            float xv = x2[v * F2 + g] + b2[g];
            xu = xu > 0.0f ? xu : 0.0f;
            xv = xv > 0.0f ? xv : 0.0f;
            s += xu * Wfc[g] + xv * Wfc[F2 + g];
        }
        float orient = 1.0f / (1.0f + expf(-s));
        out[(long)u * N + v] = orient;
        out[(long)v * N + u] = 1.0f - orient;
    }
}

extern "C" void kernel_launch(void* const* d_in, const int* in_sizes, int n_in,
                              void* d_out, int out_size, void* d_ws, size_t ws_size,
                              hipStream_t stream) {
    const float* W1  = (const float*)d_in[1];
    const float* b1  = (const float*)d_in[2];
    const float* W2  = (const float*)d_in[3];
    const float* b2  = (const float*)d_in[4];
    const float* Wfc = (const float*)d_in[5];
    const float* bfc = (const float*)d_in[6];
    const int* edge_index = (const int*)d_in[7];
    const int* und        = (const int*)d_in[8];

    int N = in_sizes[1] / F1;      // 8192
    int E = in_sizes[7] / 2;
    int U = in_sizes[8] / 2;
    const int* src = edge_index;
    const int* dst = edge_index + E;

    float* ws   = (float*)d_ws;
    float* deg  = ws;                  // N
    float* dinv = ws + N;              // N
    float* x1   = ws + 2 * N;          // 16N
    float* h2   = x1 + (long)F1 * N;   // 8N
    float* x2   = h2 + (long)F2 * N;   // 8N

    const int B = 256;

    // independent bulk fill first (write-only)
    {
        long n4 = (long)N * N / 4;
        long blocks = (n4 + B - 1) / B;
        k_fill_zero<<<(int)blocks, B, 0, stream>>>((float4*)d_out, n4);
    }
    k_scatter_ones<<<(E + B - 1) / B, B, 0, stream>>>(src, dst, (float*)d_out, E, N);

    // degree + dinv
    k_init_deg<<<(N + B - 1) / B, B, 0, stream>>>(deg, N);
    k_deg_accum<<<(E + B - 1) / B, B, 0, stream>>>(dst, deg, E);
    k_dinv_initx1<<<(N + B - 1) / B, B, 0, stream>>>(deg, dinv, W1, x1, N);

    // conv1 + layer1
    {
        long work = (long)E * F1;
        k_conv1_edges<<<(int)((work + B - 1) / B), B, 0, stream>>>(src, dst, dinv, W1, x1, E);
    }
    k_layer1_finish<<<(N + B - 1) / B, B, 0, stream>>>(dinv, b1, W2, x1, h2, x2, N);

    // conv2 (bias+relu folded into orient)
    {
        long work = (long)E * F2;
        k_conv2_edges<<<(int)((work + B - 1) / B), B, 0, stream>>>(src, dst, dinv, h2, x2, E);
    }

    // edge orientation scatter (after fill + ones)
    k_orient<<<(U + B - 1) / B, B, 0, stream>>>((const int2*)und, x2, b2, Wfc, bfc,
                                                (float*)d_out, U, N);
}

// Round 3
// 451.306 us; speedup vs baseline: 1.0941x; 1.0094x over previous
//
#include <hip/hip_runtime.h>
#include <math.h>

#define F1 16
#define F2 8

// Fused: scatter 1.0 at every directed edge position of out AND count in-degree.
__global__ void k_edges0(const int* __restrict__ src, const int* __restrict__ dst,
                         float* __restrict__ out, float* __restrict__ deg,
                         int E, int N) {
    int e = blockIdx.x * blockDim.x + threadIdx.x;
    if (e < E) {
        int s = src[e], d = dst[e];
        out[(long)s * N + d] = 1.0f;
        atomicAdd(&deg[d], 1.0f);
    }
}

// dinv = rsqrt(deg_count + 1)
__global__ void k_dinv(const float* __restrict__ deg, float* __restrict__ dinv, int N) {
    int i = blockIdx.x * blockDim.x + threadIdx.x;
    if (i < N) dinv[i] = rsqrtf(deg[i] + 1.0f);
}

// conv1 aggregation: x1[dst] += norm * W1[src]   (x1 pre-zeroed by memset)
__global__ void k_conv1_edges(const int* __restrict__ src, const int* __restrict__ dst,
                              const float* __restrict__ dinv, const float* __restrict__ W1,
                              float* __restrict__ x1, int E) {
    int id = blockIdx.x * blockDim.x + threadIdx.x;
    int e = id >> 4;
    int f = id & (F1 - 1);
    if (e < E) {
        int s = src[e], d = dst[e];
        float nrm = dinv[s] * dinv[d];
        atomicAdd(&x1[d * F1 + f], nrm * W1[s * F1 + f]);
    }
}

// r = relu(x1 + dinv^2*W1 + b1); h2 = r @ W2
__global__ void k_layer1(const float* __restrict__ dinv, const float* __restrict__ b1,
                         const float* __restrict__ W1, const float* __restrict__ W2,
                         const float* __restrict__ x1, float* __restrict__ h2, int N) {
    int i = blockIdx.x * blockDim.x + threadIdx.x;
    if (i < N) {
        float di = dinv[i];
        float sw = di * di;
        float r[F1];
        #pragma unroll
        for (int f = 0; f < F1; ++f) {
            float v = x1[i * F1 + f] + sw * W1[i * F1 + f] + b1[f];
            r[f] = v > 0.0f ? v : 0.0f;
        }
        #pragma unroll
        for (int g = 0; g < F2; ++g) {
            float acc = 0.0f;
            #pragma unroll
            for (int f = 0; f < F1; ++f)
                acc += r[f] * W2[f * F2 + g];
            h2[i * F2 + g] = acc;
        }
    }
}

// conv2 aggregation: x2[dst] += norm * h2[src]   (x2 pre-zeroed by memset)
__global__ void k_conv2_edges(const int* __restrict__ src, const int* __restrict__ dst,
                              const float* __restrict__ dinv, const float* __restrict__ h2,
                              float* __restrict__ x2, int E) {
    int id = blockIdx.x * blockDim.x + threadIdx.x;
    int e = id >> 3;
    int g = id & (F2 - 1);
    if (e < E) {
        int s = src[e], d = dst[e];
        float nrm = dinv[s] * dinv[d];
        atomicAdd(&x2[d * F2 + g], nrm * h2[s * F2 + g]);
    }
}

// Per undirected edge: finish conv2 (self term + bias + relu) inline, score, scatter.
__global__ void k_orient(const int2* __restrict__ ue, const float* __restrict__ x2,
                         const float* __restrict__ h2, const float* __restrict__ dinv,
                         const float* __restrict__ b2, const float* __restrict__ Wfc,
                         const float* __restrict__ bfc, float* __restrict__ out,
                         int U, int N) {
    int k = blockIdx.x * blockDim.x + threadIdx.x;
    if (k < U) {
        int2 e = ue[k];
        int u = e.x, v = e.y;
        float swu = dinv[u] * dinv[u];
        float swv = dinv[v] * dinv[v];
        float s = bfc[0];
        #pragma unroll
        for (int g = 0; g < F2; ++g) {
            float xu = x2[u * F2 + g] + swu * h2[u * F2 + g] + b2[g];
            float xv = x2[v * F2 + g] + swv * h2[v * F2 + g] + b2[g];
            xu = xu > 0.0f ? xu : 0.0f;
            xv = xv > 0.0f ? xv : 0.0f;
            s += xu * Wfc[g] + xv * Wfc[F2 + g];
        }
        float orient = 1.0f / (1.0f + expf(-s));
        out[(long)u * N + v] = orient;
        out[(long)v * N + u] = 1.0f - orient;
    }
}

extern "C" void kernel_launch(void* const* d_in, const int* in_sizes, int n_in,
                              void* d_out, int out_size, void* d_ws, size_t ws_size,
                              hipStream_t stream) {
    const float* W1  = (const float*)d_in[1];
    const float* b1  = (const float*)d_in[2];
    const float* W2  = (const float*)d_in[3];
    const float* b2  = (const float*)d_in[4];
    const float* Wfc = (const float*)d_in[5];
    const float* bfc = (const float*)d_in[6];
    const int* edge_index = (const int*)d_in[7];
    const int* und        = (const int*)d_in[8];

    int N = in_sizes[1] / F1;      // 8192
    int E = in_sizes[7] / 2;
    int U = in_sizes[8] / 2;
    const int* src = edge_index;
    const int* dst = edge_index + E;

    // ws layout: [deg(N) | x1(16N) | x2(8N) | dinv(N) | h2(8N)]
    float* ws   = (float*)d_ws;
    float* deg  = ws;
    float* x1   = ws + N;
    float* x2   = x1 + (long)F1 * N;
    float* dinv = x2 + (long)F2 * N;
    float* h2   = dinv + N;

    const int B = 256;

    // Zero the output (write-only; adjacency reconstructed from edge_index)
    hipMemsetAsync(d_out, 0, (size_t)N * N * sizeof(float), stream);
    // Zero deg + x1 + x2 in one contiguous memset
    hipMemsetAsync(d_ws, 0, (size_t)(N + (long)F1 * N + (long)F2 * N) * sizeof(float), stream);

    // scatter ones + degree count (fused)
    k_edges0<<<(E + B - 1) / B, B, 0, stream>>>(src, dst, (float*)d_out, deg, E, N);

    // dinv
    k_dinv<<<(N + B - 1) / B, B, 0, stream>>>(deg, dinv, N);

    // conv1 aggregation
    {
        long work = (long)E * F1;
        k_conv1_edges<<<(int)((work + B - 1) / B), B, 0, stream>>>(src, dst, dinv, W1, x1, E);
    }
    // layer1 finish (self term + bias + relu + 16x8 matmul)
    k_layer1<<<(N + B - 1) / B, B, 0, stream>>>(dinv, b1, W1, W2, x1, h2, N);

    // conv2 aggregation
    {
        long work = (long)E * F2;
        k_conv2_edges<<<(int)((work + B - 1) / B), B, 0, stream>>>(src, dst, dinv, h2, x2, E);
    }

    // orient scoring + scatter (conv2 self term + bias + relu inline)
    k_orient<<<(U + B - 1) / B, B, 0, stream>>>((const int2*)und, x2, h2, dinv, b2, Wfc, bfc,
                                                (float*)d_out, U, N);
}